// Round 4
// baseline (323.181 us; speedup 1.0000x reference)
//
#include <hip/hip_runtime.h>
#include <stdint.h>

// Problem constants (from reference)
#define BATCH 16
#define MGT 256
#define NPROP 8192
#define NUM_CLASSES 80
#define IGNORED_CLASS 80
#define NUM_FG 128
#define NUM_BG 384
#define NEGV -1e30f

// Input dtypes (R3 forensics: floats are NOT downcast — "float32 -> const float*"):
//   d_in[0] gt_boxes       [16,256,4]  float32
//   d_in[1] gt_classes     [16,256]    int32
//   d_in[2] proposal_boxes [16,8192,4] float32
//   d_in[3] rand_priority  [16,8192]   float32
// Output layout (d_out is FLOAT32; ints stored as float) — confirmed R1:
//   [0,          131072)  matched_vals    [16,8192]
//   [131072,     262144)  matched_idxs    [16,8192]
//   [262144,     270336)  sampled_idxs    [16,512]
//   [270336,     278528)  sampled_classes [16,512]
//   [278528,     286720)  sampled_gt      [16,512]

// Kernel 1: per-proposal max-IoU match over 256 gt boxes, f32, np op order.
__global__ __launch_bounds__(256) void match_kernel(
    const float* __restrict__ gt_boxes,    // [B, M, 4] f32
    const int*   __restrict__ gt_classes,  // [B, M] int32
    const float* __restrict__ prop_boxes,  // [B, N, 4] f32
    float*       __restrict__ out,         // f32 flat output
    int*         __restrict__ cls_ws,      // [B, N]
    int*         __restrict__ midx_ws)     // [B, N]
{
#pragma clang fp contract(off)
    __shared__ float sgx1[MGT], sgy1[MGT], sgx2[MGT], sgy2[MGT], sga[MGT];

    const int b   = blockIdx.y;
    const int tid = threadIdx.x;

    // stage gt boxes for this batch row (256 threads == 256 gt boxes)
    {
        const float4 g = ((const float4*)gt_boxes)[(size_t)b * MGT + tid];
        sgx1[tid] = g.x; sgy1[tid] = g.y; sgx2[tid] = g.z; sgy2[tid] = g.w;
        sga[tid]  = (g.z - g.x) * (g.w - g.y);   // area_g, np op order, no FMA
    }
    __syncthreads();

    const int n = blockIdx.x * 256 + tid;
    const float4 p = ((const float4*)prop_boxes)[(size_t)b * NPROP + n];
    const float px1 = p.x, py1 = p.y, px2 = p.z, py2 = p.w;
    const float ap  = (px2 - px1) * (py2 - py1);

    float best = -1.0f;  // all IoUs >= 0, so m=0 always wins first
    int   bidx = 0;
    for (int m = 0; m < MGT; ++m) {
        float ltx = fmaxf(sgx1[m], px1);
        float lty = fmaxf(sgy1[m], py1);
        float rbx = fminf(sgx2[m], px2);
        float rby = fminf(sgy2[m], py2);
        float w = fmaxf(rbx - ltx, 0.0f);        // clip(rb-lt, 0)
        float h = fmaxf(rby - lty, 0.0f);
        float inter = w * h;
        float uni = (sga[m] + ap) - inter;       // (area_g + area_p) - inter
        float iou = (uni > 0.0f) ? (inter / uni) : 0.0f;
        if (iou > best) { best = iou; bidx = m; }  // strict > == first-index argmax
    }

    // _sample_proposals label logic (ignored-class first, then bg override)
    const bool matched = (best >= 0.5f);
    int c = gt_classes[b * MGT + bidx];
    if (c == IGNORED_CLASS) c = -1;
    if (!matched) c = NUM_CLASSES;

    const size_t on = (size_t)b * NPROP + n;
    out[on]                          = best;
    out[(size_t)BATCH * NPROP + on]  = (float)bidx;
    cls_ws[on]  = c;
    midx_ws[on] = bidx;
}

// Kernel 2: per-batch-row stable top-k via full bitonic sort of 64-bit keys.
// key = (~ord(pri_masked) << 32) | idx  -> ascending sort == (pri desc, idx asc),
// exactly lax.top_k's stable ordering; NEG-masked entries tie at -1e30 and land
// at the back in ascending-index order (reproduces filler indices + valid mask).
__global__ __launch_bounds__(1024) void sample_kernel(
    const float* __restrict__ pri_f,    // [B, N] f32
    const int*   __restrict__ cls_ws,   // [B, N]
    const int*   __restrict__ midx_ws,  // [B, N]
    float*       __restrict__ out)      // f32 flat output
{
    __shared__ unsigned long long keys[NPROP];   // 64 KiB

    const int b   = blockIdx.x;
    const int tid = threadIdx.x;
    const float* pri  = pri_f   + (size_t)b * NPROP;
    const int*   cls  = cls_ws  + (size_t)b * NPROP;
    const int*   midx = midx_ws + (size_t)b * NPROP;

    float* s_idx = out + (size_t)2 * BATCH * NPROP + (size_t)b * 512;
    float* s_cls = s_idx + (size_t)BATCH * 512;
    float* s_gt  = s_idx + (size_t)2 * BATCH * 512;

    for (int pass = 0; pass < 2; ++pass) {
        // fill keys
        for (int i = tid; i < NPROP; i += 1024) {
            int c = cls[i];
            bool m = (pass == 0) ? (c >= 0 && c != NUM_CLASSES) : (c == NUM_CLASSES);
            float p = m ? pri[i] : NEGV;
            uint32_t bits = __float_as_uint(p);
            uint32_t ord  = (bits & 0x80000000u) ? ~bits : (bits | 0x80000000u);
            keys[i] = (((unsigned long long)(~ord)) << 32) | (uint32_t)i;
        }
        __syncthreads();

        // bitonic ascending sort
        for (int k = 2; k <= NPROP; k <<= 1) {
            for (int j = k >> 1; j > 0; j >>= 1) {
                for (int i = tid; i < NPROP; i += 1024) {
                    int ixj = i ^ j;
                    if (ixj > i) {
                        unsigned long long a = keys[i], c2 = keys[ixj];
                        bool up = ((i & k) == 0);
                        if ((a > c2) == up) { keys[i] = c2; keys[ixj] = a; }
                    }
                }
                __syncthreads();
            }
        }

        // emit top-k slots
        const int kcnt = (pass == 0) ? NUM_FG : NUM_BG;
        const int off  = (pass == 0) ? 0 : NUM_FG;
        for (int jj = tid; jj < kcnt; jj += 1024) {
            unsigned long long key = keys[jj];
            int idx = (int)(uint32_t)key;
            int c = cls[idx];
            bool valid = (pass == 0) ? (c >= 0 && c != NUM_CLASSES) : (c == NUM_CLASSES);
            s_idx[off + jj] = (float)idx;
            s_cls[off + jj] = valid ? (float)c : -1.0f;
            s_gt[off + jj]  = valid ? (float)midx[idx] : -1.0f;
        }
        __syncthreads();  // keys reused next pass
    }
}

extern "C" void kernel_launch(void* const* d_in, const int* in_sizes, int n_in,
                              void* d_out, int out_size, void* d_ws, size_t ws_size,
                              hipStream_t stream) {
    const float* gt_boxes   = (const float*)d_in[0];  // f32
    const int*   gt_classes = (const int*)d_in[1];    // int32
    const float* prop_boxes = (const float*)d_in[2];  // f32
    const float* rand_pri   = (const float*)d_in[3];  // f32
    float* out = (float*)d_out;

    int* cls_ws  = (int*)d_ws;                       // [B*N] int32
    int* midx_ws = cls_ws + (size_t)BATCH * NPROP;   // [B*N] int32  (1 MiB total)

    dim3 grid1(NPROP / 256, BATCH);
    match_kernel<<<grid1, 256, 0, stream>>>(gt_boxes, gt_classes, prop_boxes,
                                            out, cls_ws, midx_ws);

    sample_kernel<<<BATCH, 1024, 0, stream>>>(rand_pri, cls_ws, midx_ws, out);
}

// Round 5
// 105.856 us; speedup vs baseline: 3.0530x; 3.0530x over previous
//
#include <hip/hip_runtime.h>
#include <stdint.h>

// Problem constants (from reference)
#define BATCH 16
#define MGT 256
#define NPROP 8192
#define NUM_CLASSES 80
#define IGNORED_CLASS 80
#define NUM_FG 128
#define NUM_BG 384
#define SENT 0xFFFFFFFFu

typedef unsigned long long u64;

// Input dtypes (confirmed R4): gt_boxes f32[16,256,4], gt_classes i32[16,256],
// proposal_boxes f32[16,8192,4], rand_priority f32[16,8192].
// Output layout (d_out FLOAT32; ints stored as float) — confirmed R1/R4:
//   [0,131072) matched_vals | [131072,262144) matched_idxs |
//   [262144,270336) sampled_idxs | [270336,278528) sampled_classes |
//   [278528,286720) sampled_gt      (each [16,512] for the sampled chunks)

// ---------------- Kernel 1: max-IoU match, split-M x2 ----------------
// Block = 256 threads = 128 proposals x 2 halves; each half scans 128 gt.
// Combine via u64 key (iou_bits<<32 | (255-bidx)): max key == larger iou,
// tie -> smaller gt index (== np first-index argmax).
__global__ __launch_bounds__(256) void match_kernel(
    const float* __restrict__ gt_boxes,    // [B, M, 4] f32
    const int*   __restrict__ gt_classes,  // [B, M] i32
    const float* __restrict__ prop_boxes,  // [B, N, 4] f32
    float*       __restrict__ out,         // f32 flat output
    int*         __restrict__ cls_ws,      // [B, N]
    int*         __restrict__ midx_ws)     // [B, N]
{
#pragma clang fp contract(off)
    __shared__ float4 sbox[MGT];
    __shared__ float  sga[MGT];
    __shared__ u64    skey[128];

    const int b   = blockIdx.y;
    const int tid = threadIdx.x;

    {   // stage gt boxes (256 threads == 256 gt boxes)
        const float4 g = ((const float4*)gt_boxes)[(size_t)b * MGT + tid];
        sbox[tid] = g;
        sga[tid]  = (g.z - g.x) * (g.w - g.y);   // np op order, no FMA
    }
    __syncthreads();

    const int pl   = tid & 127;
    const int half = tid >> 7;
    const int n    = blockIdx.x * 128 + pl;
    const float4 p = ((const float4*)prop_boxes)[(size_t)b * NPROP + n];
    const float ap = (p.z - p.x) * (p.w - p.y);

    float best = -1.0f;
    int   bidx = 0;
    const int m0 = half * 128;
#pragma unroll 4
    for (int mm = 0; mm < 128; ++mm) {
        const int m = m0 + mm;
        const float4 g = sbox[m];
        const float ag = sga[m];
        float ltx = fmaxf(g.x, p.x);
        float lty = fmaxf(g.y, p.y);
        float rbx = fminf(g.z, p.z);
        float rby = fminf(g.w, p.w);
        float w = fmaxf(rbx - ltx, 0.0f);
        float h = fmaxf(rby - lty, 0.0f);
        float inter = w * h;
        float uni = (ag + ap) - inter;           // (area_g + area_p) - inter
        float iou = (uni > 0.0f) ? (inter / uni) : 0.0f;
        if (iou > best) { best = iou; bidx = m; }
    }
    // best >= 0 here (128 IoUs, all >= 0) -> f32 bits monotone as unsigned
    u64 key = ((u64)__float_as_uint(best) << 32) | (uint32_t)(255 - bidx);
    if (half) skey[pl] = key;
    __syncthreads();
    if (half == 0) {
        u64 o = skey[pl];
        if (o > key) key = o;
        float bestf = __uint_as_float((uint32_t)(key >> 32));
        int   bi    = 255 - (int)(key & 0xFFu);

        const bool matched = (bestf >= 0.5f);
        int c = gt_classes[b * MGT + bi];
        if (c == IGNORED_CLASS) c = -1;
        if (!matched) c = NUM_CLASSES;

        const size_t on = (size_t)b * NPROP + n;
        out[on]                         = bestf;
        out[(size_t)BATCH * NPROP + on] = (float)bi;
        cls_ws[on]  = c;
        midx_ws[on] = bi;
    }
}

// ---------------- scan helpers ----------------
__device__ __forceinline__ uint32_t wave_incl_scan_u32(uint32_t x) {
#pragma unroll
    for (int d = 1; d < 64; d <<= 1) {
        uint32_t y = __shfl_up(x, d, 64);
        if ((threadIdx.x & 63) >= d) x += y;
    }
    return x;
}

// block-wide exclusive scan (1024 threads, one value each)
__device__ __forceinline__ uint32_t block_excl_scan(uint32_t s, uint32_t* wsums) {
    const int tid = threadIdx.x, lane = tid & 63, wid = tid >> 6;
    __syncthreads();                       // protect wsums reuse across calls
    uint32_t incl = wave_incl_scan_u32(s);
    if (lane == 63) wsums[wid] = incl;
    __syncthreads();
    if (wid == 0) {
        uint32_t w  = (lane < 16) ? wsums[lane] : 0u;
        uint32_t wi = wave_incl_scan_u32(w);
        if (lane < 16) wsums[lane] = wi - w;  // exclusive wave offsets
    }
    __syncthreads();
    return wsums[wid] + (incl - s);
}

// inclusive-scan hist[4096] in place; find bin b with incl[b] >= kk > incl[b-1];
// writes *sc_b = b, *sc_p = incl[b-1] (count strictly below bin b).
__device__ __forceinline__ void scan_and_find(uint32_t* hist, uint32_t* wsums,
                                              uint32_t kk, uint32_t* sc_b, uint32_t* sc_p) {
    const int tid  = threadIdx.x;
    __syncthreads();                       // histogram atomics complete
    const int base = tid * 4;
    uint32_t v0 = hist[base], v1 = hist[base+1], v2 = hist[base+2], v3 = hist[base+3];
    uint32_t pre = block_excl_scan(v0+v1+v2+v3, wsums);
    uint32_t i0 = pre+v0, i1 = i0+v1, i2 = i1+v2, i3 = i2+v3;
    hist[base] = i0; hist[base+1] = i1; hist[base+2] = i2; hist[base+3] = i3;
    __syncthreads();
    uint32_t prev = (base == 0) ? 0u : hist[base-1];
    uint32_t inc[4] = {i0, i1, i2, i3};
#pragma unroll
    for (int j = 0; j < 4; ++j) {
        if (inc[j] >= kk && prev < kk) { *sc_b = (uint32_t)(base+j); *sc_p = prev; }
        prev = inc[j];
    }
    __syncthreads();
}

// ---------------- Kernel 2: radix-select top-k + rank scatter ----------------
// One block per (row, pass): 32 blocks, 1024 threads.
// key32 = ~ord(pri) for masked-in elements (smaller == higher priority),
// SENT for masked-out. Assumes pri >= 0 (uniform [0,1)), so real keys < 0x80000000.
// 3-level select (12+12+8 bits) finds exact k-th key H* and tie-take count k4;
// ties at H* and the filler path are resolved by ascending idx (== lax.top_k
// stability with the -1e30 masked fill).
__global__ __launch_bounds__(1024) void sample_kernel(
    const float* __restrict__ pri_f,    // [B, N] f32
    const int*   __restrict__ cls_ws,   // [B, N]
    const int*   __restrict__ midx_ws,  // [B, N]
    float*       __restrict__ out)      // f32 flat output
{
    __shared__ uint32_t h32[NPROP];     // 32 KB ordered keys
    __shared__ uint32_t hist[4096];     // 16 KB
    __shared__ uint32_t wsums[16];
    __shared__ uint32_t sc[8];          // b1,p1,b2,p2,b3,p3,C,selcount
    __shared__ u64      sel[NUM_BG];    // 3 KB (max k = 384)

    const int tid  = threadIdx.x;
    const int b    = blockIdx.x >> 1;
    const int pass = blockIdx.x & 1;
    const int K    = pass ? NUM_BG : NUM_FG;
    const int off  = pass ? NUM_FG : 0;

    const float* pri  = pri_f   + (size_t)b * NPROP;
    const int*   cls  = cls_ws  + (size_t)b * NPROP;
    const int*   midx = midx_ws + (size_t)b * NPROP;

    float* s_idx = out + (size_t)2 * BATCH * NPROP + (size_t)b * 512;
    float* s_cls = s_idx + (size_t)BATCH * 512;
    float* s_gt  = s_idx + (size_t)2 * BATCH * 512;

    if (tid < 8) sc[tid] = 0u;
    for (int i = tid; i < 4096; i += 1024) hist[i] = 0u;
    __syncthreads();

    // phase 1: build keys, count real candidates C (ballot, no hot atomics)
    uint32_t creal = 0;
#pragma unroll
    for (int it = 0; it < 8; ++it) {
        const int i = tid + it * 1024;           // coalesced
        const int c = cls[i];
        const bool m = pass ? (c == NUM_CLASSES) : (c >= 0 && c != NUM_CLASSES);
        uint32_t v = SENT;
        if (m) {
            uint32_t bits = __float_as_uint(pri[i]);
            uint32_t ord  = (bits & 0x80000000u) ? ~bits : (bits | 0x80000000u);
            v = ~ord;                            // smaller == higher priority
        }
        h32[i] = v;
        u64 bal = __ballot(m);
        if ((tid & 63) == 0) creal += __popcll(bal);
    }
    if ((tid & 63) == 0 && creal) atomicAdd(&sc[6], creal);
    __syncthreads();
    const uint32_t C    = sc[6];
    const uint32_t ksel = (C < (uint32_t)K) ? C : (uint32_t)K;

    if (C > 0) {
        // L1: bits [31:20] (real keys only; sentinel is >= 0x80000000)
        for (int i = tid; i < NPROP; i += 1024) {
            uint32_t v = h32[i];
            if (v < 0x80000000u) atomicAdd(&hist[v >> 20], 1u);
        }
        scan_and_find(hist, wsums, ksel, &sc[0], &sc[1]);
        const uint32_t b1 = sc[0], p1 = sc[1];
        const uint32_t k2 = ksel - p1;
        for (int i = tid; i < 4096; i += 1024) hist[i] = 0u;
        __syncthreads();

        // L2: bits [19:8] within bin b1
        for (int i = tid; i < NPROP; i += 1024) {
            uint32_t v = h32[i];
            if ((v >> 20) == b1) atomicAdd(&hist[(v >> 8) & 0xFFFu], 1u);
        }
        scan_and_find(hist, wsums, k2, &sc[2], &sc[3]);
        const uint32_t b2 = sc[2], p2 = sc[3];
        const uint32_t k3 = k2 - p2;
        for (int i = tid; i < 4096; i += 1024) hist[i] = 0u;
        __syncthreads();

        // L3: bits [7:0] within (b1,b2) -> exact H*
        const uint32_t top24 = (b1 << 12) | b2;
        for (int i = tid; i < NPROP; i += 1024) {
            uint32_t v = h32[i];
            if ((v >> 8) == top24) atomicAdd(&hist[v & 0xFFu], 1u);
        }
        scan_and_find(hist, wsums, k3, &sc[4], &sc[5]);
        const uint32_t b3 = sc[4], p3 = sc[5];
        const uint32_t k4 = k3 - p3;             // take k4 of the ==H* ties, idx asc
        const uint32_t Hstar = (b1 << 20) | (b2 << 8) | b3;

        // tie prefix (idx order, contiguous ownership) + compaction
        uint32_t hv[8]; uint32_t ssum = 0;
        const int cbase = tid * 8;
#pragma unroll
        for (int j = 0; j < 8; ++j) { hv[j] = h32[cbase + j]; ssum += (hv[j] == Hstar); }
        uint32_t run = block_excl_scan(ssum, wsums);
#pragma unroll
        for (int j = 0; j < 8; ++j) {
            bool take = false;
            if (hv[j] < Hstar) take = true;
            else if (hv[j] == Hstar) { take = (run < k4); ++run; }
            if (take) {
                uint32_t pos = atomicAdd(&sc[7], 1u);
                sel[pos] = ((u64)hv[j] << 32) | (uint32_t)(cbase + j);
            }
        }
        __syncthreads();
        const uint32_t S = sc[7];                // == ksel

        // rank scatter: rank = #(keys < mine); unique (idx in low bits)
        for (uint32_t j = tid; j < S; j += 1024) {
            const u64 kj = sel[j];
            uint32_t r = 0;
            for (uint32_t i = 0; i < S; ++i) r += (sel[i] < kj);  // LDS broadcast
            const uint32_t idx = (uint32_t)kj;
            s_idx[off + r] = (float)idx;
            s_cls[off + r] = (float)cls[idx];    // bg rows naturally give 80
            s_gt[off + r]  = (float)midx[idx];
        }
    }

    // filler: first (K - ksel) masked-out indices, ascending (invalid slots)
    if (ksel < (uint32_t)K) {
        const uint32_t F = (uint32_t)K - ksel;
        uint32_t hv[8]; uint32_t ssum = 0;
        const int cbase = tid * 8;
#pragma unroll
        for (int j = 0; j < 8; ++j) { hv[j] = h32[cbase + j]; ssum += (hv[j] == SENT); }
        uint32_t run = block_excl_scan(ssum, wsums);
#pragma unroll
        for (int j = 0; j < 8; ++j) {
            if (hv[j] == SENT) {
                if (run < F) {
                    const int slot = off + (int)ksel + (int)run;
                    s_idx[slot] = (float)(cbase + j);
                    s_cls[slot] = -1.0f;
                    s_gt[slot]  = -1.0f;
                }
                ++run;
            }
        }
    }
}

extern "C" void kernel_launch(void* const* d_in, const int* in_sizes, int n_in,
                              void* d_out, int out_size, void* d_ws, size_t ws_size,
                              hipStream_t stream) {
    const float* gt_boxes   = (const float*)d_in[0];
    const int*   gt_classes = (const int*)d_in[1];
    const float* prop_boxes = (const float*)d_in[2];
    const float* rand_pri   = (const float*)d_in[3];
    float* out = (float*)d_out;

    int* cls_ws  = (int*)d_ws;                      // [B*N] i32
    int* midx_ws = cls_ws + (size_t)BATCH * NPROP;  // [B*N] i32

    dim3 grid1(NPROP / 128, BATCH);                 // 64 x 16 = 1024 blocks
    match_kernel<<<grid1, 256, 0, stream>>>(gt_boxes, gt_classes, prop_boxes,
                                            out, cls_ws, midx_ws);

    sample_kernel<<<BATCH * 2, 1024, 0, stream>>>(rand_pri, cls_ws, midx_ws, out);
}